// Round 7
// baseline (315.379 us; speedup 1.0000x reference)
//
#include <hip/hip_runtime.h>

// Problem constants
#define B_    1024
#define C_    128
#define ELL   16
#define EQ    3
#define E_    10
#define P3    23
#define P2    5
#define NSEG  176            // padded segment row: 16 f4-aligned v-segments
#define RSTR  180            // row stride (180%32=20 -> 8 bank-starts x2 = 2-way, free)
#define SRS   (48 * RSTR)    // 8640 floats per (e,c) S-slice
#define KD    28             // folded weight depth: 23 (wmax) + 5 (w2)

// packed fp32 pair: clang emits v_pk_fma_f32 / v_pk_mul_f32 for <2 x float>
typedef float v2f __attribute__((ext_vector_type(2)));

// ws layout (bytes)
#define WS_CNT   0
#define WS_LIST  64
#define WS_S     65536       // S slices: 10*128*8640*4 = 44.2 MB (ws >= 66 MB, r1-r9)

// segment offsets: v-th segment holds [lin_v, Q_vv, Q_v,v+1, .., Q_v,15, pad0s]
// lengths (real) 17-v, padded to x4: {20,16,16,16,16,12,12,12,12,8,8,8,8,4,4,4}
#define SEG_OFF_INIT {0,20,36,52,68,84,96,108,120,132,140,148,156,164,168,172}

// DPP row_ror add: lane i += lane (i+N) mod 16 within its 16-lane DPP row.
// Chained over N=1,2,4,8 this is a width-16 sum-to-all; for lanes with
// xx==0 the addition tree is bit-identical to the old __shfl_xor butterfly.
// Moves the reduction off the LDS pipe (ds_bpermute) onto the VALU.
template <int CTRL>
__device__ __forceinline__ float dpp_ror_add(float v) {
    int s = __float_as_int(v);
    int r = __builtin_amdgcn_update_dpp(s, s, CTRL, 0xF, 0xF, false);
    return v + __int_as_float(r);
}
__device__ __forceinline__ float row16_sum(float v) {
    v = dpp_ror_add<0x121>(v);   // row_ror:1
    v = dpp_ror_add<0x122>(v);   // row_ror:2
    v = dpp_ror_add<0x124>(v);   // row_ror:4
    v = dpp_ror_add<0x128>(v);   // row_ror:8
    return v;
}

// ---------------------------------------------------------------------------
// Bucketing: bucket batch indices by element, pad each bucket to x128 by
// replicating the last real index (k_main r18 uses 128-row chunks; padded
// slots need no load guards; cp <= B_ always since (1024+127)&~127 = 1024).
__device__ void do_lists(const float* __restrict__ y, int* __restrict__ cnt_g,
                         int* __restrict__ list_g, int t) {
    __shared__ int lcnt[E_];
    if (t < E_) lcnt[t] = 0;
    __syncthreads();
    for (int r = 0; r < 4; ++r) {
        int b = t + 256 * r;
        int e = 0;
        #pragma unroll
        for (int j = 1; j < E_; ++j)
            if (y[b * E_ + j] > 0.5f) e = j;
        int slot = atomicAdd(&lcnt[e], 1);
        list_g[e * B_ + slot] = b;
    }
    __syncthreads();
    if (t < E_) {
        int c0 = lcnt[t];
        cnt_g[t] = c0;
        int last = (c0 > 0) ? list_g[t * B_ + c0 - 1] : 0;
        int cp = (c0 + 127) & ~127;
        if (cp > B_) cp = B_;
        for (int s2 = c0; s2 < cp; ++s2) list_g[t * B_ + s2] = last;
    }
}

// ---------------------------------------------------------------------------
// k_s r17 (UNCHANGED -- verified win): restructured slot-parallel phase 2
// with packed v_pk_fma_f32; total dropped 127.5 -> 124.2 with k_main flat.
__global__ __launch_bounds__(256, 2) void k_s(const float* __restrict__ U3,
                                              const float* __restrict__ U2,
                                              const float* __restrict__ wmax,
                                              const float* __restrict__ w2,
                                              const float* __restrict__ y,
                                              float* __restrict__ Sg,
                                              int* __restrict__ cnt_g,
                                              int* __restrict__ list_g) {
    const int t = threadIdx.x;
    if (blockIdx.x == 48) {
        if (blockIdx.y == 0 && blockIdx.z == 0) do_lists(y, cnt_g, list_g, t);
        return;
    }
    __shared__ __align__(16) float wsm[KD * 32];          //  3,584 B
    __shared__ __align__(16) float SKL[NSEG * KD];        // 19,712 B

    const int j  = blockIdx.x;
    const int e  = blockIdx.y;
    const int cq = blockIdx.z;

    // ---- phase 1a: folded weight table (23 wmax + 5 w2) for this (e, cq)
    for (int idx = t; idx < KD * 32; idx += 256) {
        int k = idx >> 5, cc = idx & 31, c = cq * 32 + cc;
        wsm[idx] = (k < 23) ? wmax[(e * P3 + k) * C_ + c]
                            : w2[(e * P2 + (k - 23)) * C_ + c];
    }

    // ---- phase 1b: symmetrized coefficient rows, straight from global U3/U2
    if (t < NSEG) {
        const int SO[16] = SEG_OFF_INIT;
        int v = 0;
        #pragma unroll
        for (int s = 1; s < 16; ++s) v += (t >= SO[s]) ? 1 : 0;
        const int l    = t - SO[v];
        const int real = 17 - v;

        float row[KD];
        #pragma unroll
        for (int d = 0; d < KD; ++d) row[d] = 0.f;

        if (l == 0) {
            #pragma unroll
            for (int q = 0; q < P2; ++q)
                row[23 + q] = U2[(size_t)j * (ELL * P2) + v * P2 + q];
        } else if (l < real) {
            int i = v + l - 1;
            const float* pa = U3 + (size_t)j * (ELL * ELL * P3) + (v * ELL + i) * P3;
            const float* pb = U3 + (size_t)j * (ELL * ELL * P3) + (i * ELL + v) * P3;
            if (i != v) {
                #pragma unroll
                for (int k = 0; k < P3; ++k) row[k] = pa[k] + pb[k];
            } else {
                #pragma unroll
                for (int k = 0; k < P3; ++k) row[k] = pa[k];
            }
        }   // else: pad slot -> stays zero

        float* dst = &SKL[t * KD];
        #pragma unroll
        for (int d4 = 0; d4 < KD / 4; ++d4)
            *(float4*)(dst + 4 * d4) = make_float4(row[4 * d4], row[4 * d4 + 1],
                                                   row[4 * d4 + 2], row[4 * d4 + 3]);
    }
    __syncthreads();

    if (t >= NSEG) return;

    // ---- phase 2: 4 slots x 8 c per thread, packed fp32
    const int sg = t % 44;          // slot group: slots sg, sg+44, sg+88, sg+132
    const int cg = t / 44;          // 0..3 -> c8 = cg*8
    const int c8 = cg * 8;

    v2f acc[4][4];                  // [s][c-pair]
    #pragma unroll
    for (int s = 0; s < 4; ++s)
        #pragma unroll
        for (int cp2 = 0; cp2 < 4; ++cp2) acc[s][cp2] = (v2f){0.f, 0.f};

    #pragma unroll
    for (int k4 = 0; k4 < KD / 4; ++k4) {
        float4 sk4[4];
        #pragma unroll
        for (int s = 0; s < 4; ++s)
            sk4[s] = *(const float4*)&SKL[(sg + 44 * s) * KD + 4 * k4];
        #pragma unroll
        for (int kk = 0; kk < 4; ++kk) {
            const int k = 4 * k4 + kk;
            float4 w0 = *(const float4*)&wsm[k * 32 + c8];
            float4 w1 = *(const float4*)&wsm[k * 32 + c8 + 4];
            v2f wp0 = {w0.x, w0.y}, wp1 = {w0.z, w0.w};
            v2f wp2 = {w1.x, w1.y}, wp3 = {w1.z, w1.w};
            #pragma unroll
            for (int s = 0; s < 4; ++s) {
                const float skv = (kk == 0) ? sk4[s].x : (kk == 1) ? sk4[s].y
                                : (kk == 2) ? sk4[s].z : sk4[s].w;
                acc[s][0] += skv * wp0;
                acc[s][1] += skv * wp1;
                acc[s][2] += skv * wp2;
                acc[s][3] += skv * wp3;
            }
        }
    }

    // ---- stores: lane-consecutive in slot -> coalesced 44-lane runs
    #pragma unroll
    for (int s = 0; s < 4; ++s) {
        const int slot = sg + 44 * s;
        #pragma unroll
        for (int cc = 0; cc < 8; ++cc) {
            const int c = cq * 32 + c8 + cc;
            Sg[(size_t)(e * C_ + c) * SRS + j * RSTR + slot] = acc[s][cc >> 1][cc & 1];
        }
    }
}

// ---------------------------------------------------------------------------
// k_main r18b (= r18 resubmitted; r18 bench was an infra failure, no data):
// attack the LDS pipe (the r17-identified bottleneck).
// r17 post-mortem: halving FMA issue (VALUBusy 78->52%) left dur FLAT at
// ~45us -> VALU is not the critical pipe. LDS-pipe model: 44 ds_read_b128
// (~12cy) + 16 ds_bpermute shuffles per wave-chunk ~ 720cy; x 4 waves x 2
// chunks x 15 blocks/CU ~ 34us @2.4GHz -- matches measured. Two cuts:
//  1. EIGHT rows/thread (4 v2f pairs): each of the 44 u-reads now feeds 8
//     rows -> LDS reads per unit work HALVE; one 128-row chunk replaces two
//     64-row chunks (one barrier segment, one gather window). This is NOT
//     r13: r13 kept both halves' reads (clobber blocked CSE) and paid VGPR
//     for zero LDS savings; here the shared read IS the change.
//     do_lists pads buckets to x128 so no load guards needed.
//  2. Butterfly via DPP row_ror adds (VALU pipe) instead of __shfl_xor
//     (ds_bpermute, LDS pipe). Bit-identical tree for the storing lanes.
// VGPR ~112 expected; __launch_bounds__(256,4) caps allocator at 128.
// Tripwire: VGPR=128 + scratch -> revert to R=4 + DPP only.
__global__ __launch_bounds__(256, 4) void k_main(
    const float* __restrict__ x, const float* __restrict__ Sg,
    const float* __restrict__ U1, const float* __restrict__ w1,
    const int* __restrict__ cnt_g, const int* __restrict__ list_g,
    float* __restrict__ out) {

    __shared__ __align__(16) float V3L[16 * RSTR];   // 11,520 B

    const int t  = threadIdx.x;
    const int bx = blockIdx.x;
    const int w  = bx % 3, c = bx / 3;
    const int e  = blockIdx.y;
    const int xx = t & 15, bs = t >> 4;
    const int cnt  = cnt_g[e];
    const int cntp = (cnt + 127) & ~127;   // matches do_lists 128-pad

    // ---- fill V3L: this w's 16 rows = 2880 floats = 720 f4, straight copy
    {
        const float4* src = (const float4*)(Sg + (size_t)(e * C_ + c) * SRS
                                            + (size_t)w * 16 * RSTR);
        float4* dst = (float4*)V3L;
        #pragma unroll
        for (int r = 0; r < 2; ++r) dst[t + 256 * r] = src[t + 256 * r];
        if (t < 208) dst[512 + t] = src[512 + t];
    }
    const float v1x = U1[w * 16 + xx] * w1[e * C_ + c];
    __syncthreads();

    const float* v3p = &V3L[xx * RSTR];
    const int SO[16] = SEG_OFF_INIT;

    // ---- chunk loop: 128 rows per chunk, 8 per thread (usually 1 iter) ----
    #pragma clang loop unroll(disable)
    for (int base = 0; base < cntp; base += 128) {
        __syncthreads();   // anti-LICM liveness pin (r5/r6 lesson)

        const int slot = base + bs * 8;
        int bidx[8];
        #pragma unroll
        for (int r = 0; r < 8; ++r) bidx[r] = list_g[e * B_ + slot + r];

        // xm2[p][i] = (x_{r=2p}[i], x_{r=2p+1}[i]) -- packed pair layout
        v2f xm2[4][16];
        float xo[8];
        #pragma unroll
        for (int r = 0; r < 8; ++r) {
            const float* xb = x + ((size_t)bidx[r] * C_ + c) * ELL;
            #pragma unroll
            for (int i4 = 0; i4 < 4; ++i4) {
                float4 a = ((const float4*)xb)[i4];
                xm2[r >> 1][4 * i4 + 0][r & 1] = a.x;
                xm2[r >> 1][4 * i4 + 1][r & 1] = a.y;
                xm2[r >> 1][4 * i4 + 2][r & 1] = a.z;
                xm2[r >> 1][4 * i4 + 3][r & 1] = a.w;
            }
            xo[r] = xb[xx];   // own-x element (L1 hit; no dynamic reg index)
        }

        v2f t2p[4] = {(v2f){0.f, 0.f}, (v2f){0.f, 0.f},
                      (v2f){0.f, 0.f}, (v2f){0.f, 0.f}};
        #pragma unroll
        for (int v = 0; v < 16; ++v) {
            const int off = SO[v];
            const int nf4 = (v == 0) ? 5 : (v < 5) ? 4 : (v < 9) ? 3 : (v < 13) ? 2 : 1;
            v2f inner[4];
            {   // first f4: [lin, Q_vv, Q_v,v+1, Q_v,v+2] -- read ONCE, use x4
                float4 u = *(const float4*)(v3p + off);
                #pragma unroll
                for (int p = 0; p < 4; ++p) {
                    v2f s = u.x + u.y * xm2[p][v];
                    if (v + 1 <= 15) s += u.z * xm2[p][v + 1];
                    if (v + 2 <= 15) s += u.w * xm2[p][v + 2];
                    inner[p] = s;
                }
            }
            #pragma unroll
            for (int q = 1; q < nf4; ++q) {
                float4 u = *(const float4*)(v3p + off + 4 * q);
                const int i0 = v + 4 * q - 1;
                #pragma unroll
                for (int p = 0; p < 4; ++p) {
                    inner[p] += u.x * xm2[p][i0];
                    if (i0 + 1 <= 15) inner[p] += u.y * xm2[p][i0 + 1];
                    if (i0 + 2 <= 15) inner[p] += u.z * xm2[p][i0 + 2];
                    if (i0 + 3 <= 15) inner[p] += u.w * xm2[p][i0 + 3];
                }
            }
            #pragma unroll
            for (int p = 0; p < 4; ++p) t2p[p] += xm2[p][v] * inner[p];
        }

        // out[b,c,w] = sum_xx (t2 + v1[xx]) * x[xx]  -- DPP row-16 reduction
        float cv[8];
        #pragma unroll
        for (int r = 0; r < 8; ++r)
            cv[r] = (t2p[r >> 1][r & 1] + v1x) * xo[r];
        #pragma unroll
        for (int r = 0; r < 8; ++r) cv[r] = row16_sum(cv[r]);
        if (xx == 0) {
            #pragma unroll
            for (int r = 0; r < 8; ++r)
                if (slot + r < cnt)
                    out[(size_t)bidx[r] * (C_ * EQ) + c * EQ + w] = cv[r];
        }
    }
}

// ---------------------------------------------------------------------------
extern "C" void kernel_launch(void* const* d_in, const int* in_sizes, int n_in,
                              void* d_out, int out_size, void* d_ws, size_t ws_size,
                              hipStream_t stream) {
    const float* x    = (const float*)d_in[0];
    const float* y    = (const float*)d_in[1];
    const float* U3   = (const float*)d_in[2];
    const float* U2   = (const float*)d_in[3];
    const float* U1   = (const float*)d_in[4];
    const float* wmax = (const float*)d_in[5];
    const float* w2   = (const float*)d_in[6];
    const float* w1   = (const float*)d_in[7];
    float* out = (float*)d_out;
    char*  ws  = (char*)d_ws;

    int*   cnt_g  = (int*)(ws + WS_CNT);
    int*   list_g = (int*)(ws + WS_LIST);
    float* Sg     = (float*)(ws + WS_S);
    (void)ws_size;   // 44.3 MB needed; harness ws confirmed >= 66 MB (r1-r9)

    k_s<<<dim3(49, E_, 4), 256, 0, stream>>>(U3, U2, wmax, w2, y, Sg, cnt_g, list_g);
    k_main<<<dim3(C_ * EQ, E_), 256, 0, stream>>>(x, Sg, U1, w1, cnt_g, list_g, out);
}

// Round 8
// 123.342 us; speedup vs baseline: 2.5569x; 2.5569x over previous
//
#include <hip/hip_runtime.h>

// Problem constants
#define B_    1024
#define C_    128
#define ELL   16
#define EQ    3
#define E_    10
#define P3    23
#define P2    5
#define NSEG  176            // padded segment row: 16 f4-aligned v-segments
#define RSTR  180            // row stride (180%32=20 -> 8 bank-starts x2 = 2-way, free)
#define SRS   (48 * RSTR)    // 8640 floats per (e,c) S-slice
#define KD    28             // folded weight depth: 23 (wmax) + 5 (w2)

// packed fp32 pair: clang emits v_pk_fma_f32 / v_pk_mul_f32 for <2 x float>
typedef float v2f __attribute__((ext_vector_type(2)));

// ws layout (bytes)
#define WS_CNT   0
#define WS_LIST  64
#define WS_S     65536       // S slices: 10*128*8640*4 = 44.2 MB (ws >= 66 MB, r1-r9)

// segment offsets: v-th segment holds [lin_v, Q_vv, Q_v,v+1, .., Q_v,15, pad0s]
// lengths (real) 17-v, padded to x4: {20,16,16,16,16,12,12,12,12,8,8,8,8,4,4,4}
#define SEG_OFF_INIT {0,20,36,52,68,84,96,108,120,132,140,148,156,164,168,172}

// DPP row_ror add: lane i += lane (i+N) mod 16 within its 16-lane DPP row.
// Chained over N=1,2,4,8 this is a width-16 sum-to-all; for the storing
// lanes (xx==0) the addition tree is bit-identical to the __shfl_xor
// butterfly. Runs on the VALU -- removes 16 ds_bpermute (LDS pipe) per
// thread-chunk. Functionally VERIFIED in r18b (passed, absmax identical).
template <int CTRL>
__device__ __forceinline__ float dpp_ror_add(float v) {
    int s = __float_as_int(v);
    int r = __builtin_amdgcn_update_dpp(s, s, CTRL, 0xF, 0xF, false);
    return v + __int_as_float(r);
}
__device__ __forceinline__ float row16_sum(float v) {
    v = dpp_ror_add<0x121>(v);   // row_ror:1
    v = dpp_ror_add<0x122>(v);   // row_ror:2
    v = dpp_ror_add<0x124>(v);   // row_ror:4
    v = dpp_ror_add<0x128>(v);   // row_ror:8
    return v;
}

// ---------------------------------------------------------------------------
// Bucketing: bucket batch indices by element, pad each bucket to x64 by
// replicating the last real index (k_main needs no load guards). Exact r14.
__device__ void do_lists(const float* __restrict__ y, int* __restrict__ cnt_g,
                         int* __restrict__ list_g, int t) {
    __shared__ int lcnt[E_];
    if (t < E_) lcnt[t] = 0;
    __syncthreads();
    for (int r = 0; r < 4; ++r) {
        int b = t + 256 * r;
        int e = 0;
        #pragma unroll
        for (int j = 1; j < E_; ++j)
            if (y[b * E_ + j] > 0.5f) e = j;
        int slot = atomicAdd(&lcnt[e], 1);
        list_g[e * B_ + slot] = b;
    }
    __syncthreads();
    if (t < E_) {
        int c0 = lcnt[t];
        cnt_g[t] = c0;
        int last = (c0 > 0) ? list_g[t * B_ + c0 - 1] : 0;
        int cp = (c0 + 63) & ~63;
        if (cp > B_) cp = B_;
        for (int s2 = c0; s2 < cp; ++s2) list_g[t * B_ + s2] = last;
    }
}

// ---------------------------------------------------------------------------
// k_s r17 (UNCHANGED -- verified win): restructured slot-parallel phase 2
// with packed v_pk_fma_f32; total dropped 127.5 -> 124.2 with k_main flat.
__global__ __launch_bounds__(256, 2) void k_s(const float* __restrict__ U3,
                                              const float* __restrict__ U2,
                                              const float* __restrict__ wmax,
                                              const float* __restrict__ w2,
                                              const float* __restrict__ y,
                                              float* __restrict__ Sg,
                                              int* __restrict__ cnt_g,
                                              int* __restrict__ list_g) {
    const int t = threadIdx.x;
    if (blockIdx.x == 48) {
        if (blockIdx.y == 0 && blockIdx.z == 0) do_lists(y, cnt_g, list_g, t);
        return;
    }
    __shared__ __align__(16) float wsm[KD * 32];          //  3,584 B
    __shared__ __align__(16) float SKL[NSEG * KD];        // 19,712 B

    const int j  = blockIdx.x;
    const int e  = blockIdx.y;
    const int cq = blockIdx.z;

    // ---- phase 1a: folded weight table (23 wmax + 5 w2) for this (e, cq)
    for (int idx = t; idx < KD * 32; idx += 256) {
        int k = idx >> 5, cc = idx & 31, c = cq * 32 + cc;
        wsm[idx] = (k < 23) ? wmax[(e * P3 + k) * C_ + c]
                            : w2[(e * P2 + (k - 23)) * C_ + c];
    }

    // ---- phase 1b: symmetrized coefficient rows, straight from global U3/U2
    if (t < NSEG) {
        const int SO[16] = SEG_OFF_INIT;
        int v = 0;
        #pragma unroll
        for (int s = 1; s < 16; ++s) v += (t >= SO[s]) ? 1 : 0;
        const int l    = t - SO[v];
        const int real = 17 - v;

        float row[KD];
        #pragma unroll
        for (int d = 0; d < KD; ++d) row[d] = 0.f;

        if (l == 0) {
            #pragma unroll
            for (int q = 0; q < P2; ++q)
                row[23 + q] = U2[(size_t)j * (ELL * P2) + v * P2 + q];
        } else if (l < real) {
            int i = v + l - 1;
            const float* pa = U3 + (size_t)j * (ELL * ELL * P3) + (v * ELL + i) * P3;
            const float* pb = U3 + (size_t)j * (ELL * ELL * P3) + (i * ELL + v) * P3;
            if (i != v) {
                #pragma unroll
                for (int k = 0; k < P3; ++k) row[k] = pa[k] + pb[k];
            } else {
                #pragma unroll
                for (int k = 0; k < P3; ++k) row[k] = pa[k];
            }
        }   // else: pad slot -> stays zero

        float* dst = &SKL[t * KD];
        #pragma unroll
        for (int d4 = 0; d4 < KD / 4; ++d4)
            *(float4*)(dst + 4 * d4) = make_float4(row[4 * d4], row[4 * d4 + 1],
                                                   row[4 * d4 + 2], row[4 * d4 + 3]);
    }
    __syncthreads();

    if (t >= NSEG) return;

    // ---- phase 2: 4 slots x 8 c per thread, packed fp32
    const int sg = t % 44;          // slot group: slots sg, sg+44, sg+88, sg+132
    const int cg = t / 44;          // 0..3 -> c8 = cg*8
    const int c8 = cg * 8;

    v2f acc[4][4];                  // [s][c-pair]
    #pragma unroll
    for (int s = 0; s < 4; ++s)
        #pragma unroll
        for (int cp2 = 0; cp2 < 4; ++cp2) acc[s][cp2] = (v2f){0.f, 0.f};

    #pragma unroll
    for (int k4 = 0; k4 < KD / 4; ++k4) {
        float4 sk4[4];
        #pragma unroll
        for (int s = 0; s < 4; ++s)
            sk4[s] = *(const float4*)&SKL[(sg + 44 * s) * KD + 4 * k4];
        #pragma unroll
        for (int kk = 0; kk < 4; ++kk) {
            const int k = 4 * k4 + kk;
            float4 w0 = *(const float4*)&wsm[k * 32 + c8];
            float4 w1 = *(const float4*)&wsm[k * 32 + c8 + 4];
            v2f wp0 = {w0.x, w0.y}, wp1 = {w0.z, w0.w};
            v2f wp2 = {w1.x, w1.y}, wp3 = {w1.z, w1.w};
            #pragma unroll
            for (int s = 0; s < 4; ++s) {
                const float skv = (kk == 0) ? sk4[s].x : (kk == 1) ? sk4[s].y
                                : (kk == 2) ? sk4[s].z : sk4[s].w;
                acc[s][0] += skv * wp0;
                acc[s][1] += skv * wp1;
                acc[s][2] += skv * wp2;
                acc[s][3] += skv * wp3;
            }
        }
    }

    // ---- stores: lane-consecutive in slot -> coalesced 44-lane runs
    #pragma unroll
    for (int s = 0; s < 4; ++s) {
        const int slot = sg + 44 * s;
        #pragma unroll
        for (int cc = 0; cc < 8; ++cc) {
            const int c = cq * 32 + c8 + cc;
            Sg[(size_t)(e * C_ + c) * SRS + j * RSTR + slot] = acc[s][cc >> 1][cc & 1];
        }
    }
}

// ---------------------------------------------------------------------------
// k_main r19 = EXACT r14 body (verified best: 43.2us, VGPR 64, occ 33%)
// with ONE change: __shfl_xor butterfly -> DPP row16_sum (VALU pipe).
// r18b post-mortem (231us CATASTROPHE): 8 rows/thread put 128+ floats live
// -> scratch spill (WRITE_SIZE 12->502 MB, FETCH 46->348 MB). Register
// budget caps row-reuse at 4 rows / 64 live floats -- r13 and r18 both
// died on this wall. The DPP reduction was the zero-register half of the
// LDS-pipe cut and is functionally verified (r18b passed): removes 16
// ds_bpermute of the 60 LDS-pipe instrs per thread-chunk (-27%).
// CRITICAL (unchanged): __syncthreads() pin + unroll(disable) -- LICM
// hoisting LDS reads caused the r5/r6 VGPR blowup/spill.
__global__ __launch_bounds__(256, 2) void k_main(
    const float* __restrict__ x, const float* __restrict__ Sg,
    const float* __restrict__ U1, const float* __restrict__ w1,
    const int* __restrict__ cnt_g, const int* __restrict__ list_g,
    float* __restrict__ out) {

    __shared__ __align__(16) float V3L[16 * RSTR];   // 11,520 B

    const int t  = threadIdx.x;
    const int bx = blockIdx.x;
    const int w  = bx % 3, c = bx / 3;
    const int e  = blockIdx.y;
    const int xx = t & 15, bs = t >> 4;
    const int cnt  = cnt_g[e];
    const int cntp = (cnt + 63) & ~63;

    // ---- fill V3L: this w's 16 rows = 2880 floats = 720 f4, straight copy
    {
        const float4* src = (const float4*)(Sg + (size_t)(e * C_ + c) * SRS
                                            + (size_t)w * 16 * RSTR);
        float4* dst = (float4*)V3L;
        #pragma unroll
        for (int r = 0; r < 2; ++r) dst[t + 256 * r] = src[t + 256 * r];
        if (t < 208) dst[512 + t] = src[512 + t];
    }
    const float v1x = U1[w * 16 + xx] * w1[e * C_ + c];
    __syncthreads();

    const float* v3p = &V3L[xx * RSTR];
    const int SO[16] = SEG_OFF_INIT;

    // ---- chunk loop: 64 rows per chunk, 4 per thread ----
    #pragma clang loop unroll(disable)
    for (int base = 0; base < cntp; base += 64) {
        __syncthreads();   // anti-LICM liveness pin (see header note)

        const int slot = base + bs * 4;
        int bidx[4];
        #pragma unroll
        for (int r = 0; r < 4; ++r) bidx[r] = list_g[e * B_ + slot + r];

        float xm[4][16];
        float xo[4];
        #pragma unroll
        for (int r = 0; r < 4; ++r) {
            const float* xb = x + ((size_t)bidx[r] * C_ + c) * ELL;
            #pragma unroll
            for (int i4 = 0; i4 < 4; ++i4) {
                float4 a = ((const float4*)xb)[i4];
                xm[r][4 * i4 + 0] = a.x; xm[r][4 * i4 + 1] = a.y;
                xm[r][4 * i4 + 2] = a.z; xm[r][4 * i4 + 3] = a.w;
            }
            xo[r] = xb[xx];   // own-x element (L1 hit; no dynamic reg index)
        }

        float t2[4] = {0.f, 0.f, 0.f, 0.f};
        #pragma unroll
        for (int v = 0; v < 16; ++v) {
            const int off = SO[v];
            const int nf4 = (v == 0) ? 5 : (v < 5) ? 4 : (v < 9) ? 3 : (v < 13) ? 2 : 1;
            float inner[4];
            {   // first f4: [lin, Q_vv, Q_v,v+1, Q_v,v+2]
                float4 u = *(const float4*)(v3p + off);
                #pragma unroll
                for (int r = 0; r < 4; ++r) {
                    float s = u.x + u.y * xm[r][v];
                    if (v + 1 <= 15) s += u.z * xm[r][v + 1];
                    if (v + 2 <= 15) s += u.w * xm[r][v + 2];
                    inner[r] = s;
                }
            }
            #pragma unroll
            for (int q = 1; q < nf4; ++q) {
                float4 u = *(const float4*)(v3p + off + 4 * q);
                const int i0 = v + 4 * q - 1;
                #pragma unroll
                for (int r = 0; r < 4; ++r) {
                    inner[r] += u.x * xm[r][i0];
                    if (i0 + 1 <= 15) inner[r] += u.y * xm[r][i0 + 1];
                    if (i0 + 2 <= 15) inner[r] += u.z * xm[r][i0 + 2];
                    if (i0 + 3 <= 15) inner[r] += u.w * xm[r][i0 + 3];
                }
            }
            #pragma unroll
            for (int r = 0; r < 4; ++r) t2[r] += xm[r][v] * inner[r];
        }

        // out[b,c,w] = sum_xx (t2 + v1[xx]) * x[xx]  -- DPP row-16 reduction
        float cv[4];
        #pragma unroll
        for (int r = 0; r < 4; ++r) cv[r] = (t2[r] + v1x) * xo[r];
        #pragma unroll
        for (int r = 0; r < 4; ++r) cv[r] = row16_sum(cv[r]);
        if (xx == 0) {
            #pragma unroll
            for (int r = 0; r < 4; ++r)
                if (slot + r < cnt)
                    out[(size_t)bidx[r] * (C_ * EQ) + c * EQ + w] = cv[r];
        }
    }
}

// ---------------------------------------------------------------------------
extern "C" void kernel_launch(void* const* d_in, const int* in_sizes, int n_in,
                              void* d_out, int out_size, void* d_ws, size_t ws_size,
                              hipStream_t stream) {
    const float* x    = (const float*)d_in[0];
    const float* y    = (const float*)d_in[1];
    const float* U3   = (const float*)d_in[2];
    const float* U2   = (const float*)d_in[3];
    const float* U1   = (const float*)d_in[4];
    const float* wmax = (const float*)d_in[5];
    const float* w2   = (const float*)d_in[6];
    const float* w1   = (const float*)d_in[7];
    float* out = (float*)d_out;
    char*  ws  = (char*)d_ws;

    int*   cnt_g  = (int*)(ws + WS_CNT);
    int*   list_g = (int*)(ws + WS_LIST);
    float* Sg     = (float*)(ws + WS_S);
    (void)ws_size;   // 44.3 MB needed; harness ws confirmed >= 66 MB (r1-r9)

    k_s<<<dim3(49, E_, 4), 256, 0, stream>>>(U3, U2, wmax, w2, y, Sg, cnt_g, list_g);
    k_main<<<dim3(C_ * EQ, E_), 256, 0, stream>>>(x, Sg, U1, w1, cnt_g, list_g, out);
}